// Round 1
// baseline (4214.783 us; speedup 1.0000x reference)
//
#include <hip/hip_runtime.h>
#include <hip/hip_bf16.h>
#include <math.h>

// Problem constants
#define TOKENS   16384        // T*Z
#define DDIM     1024
#define NEXP     64
#define PSLOT    32
#define NSLOTS   2048         // NEXP*PSLOT
#define HDIM     1024
#define LN_EPS   1e-5f

// ---------------------------------------------------------------------------
// Generic tiled fp32 GEMM: C[M,N] = op(A) * op(B)  (+ bias over N)
//  TA=false: A stored [M,K] ; TA=true: A stored [K,M]
//  TB=false: B stored [K,N] ; TB=true: B stored [N,K]
// Tile 128x128, BK=16, 256 threads, 8x8 per thread (4+4 split fragments).
// ---------------------------------------------------------------------------
template<bool TA, bool TB, bool BIAS_N>
__global__ __launch_bounds__(256) void gemm_f32(
    const float* __restrict__ A, const float* __restrict__ B,
    const float* __restrict__ bias, float* __restrict__ C,
    int M, int N, int K)
{
    constexpr int BM = 128, BN = 128, BK = 16;
    __shared__ float As[BK][BM + 4];   // k-major
    __shared__ float Bs[BK][BN + 4];   // k-major

    const int tid = threadIdx.x;
    const int n0 = blockIdx.x * BN;
    const int m0 = blockIdx.y * BM;
    const int tx = tid & 15;           // 0..15
    const int ty = tid >> 4;           // 0..15

    float acc[8][8];
#pragma unroll
    for (int i = 0; i < 8; ++i)
#pragma unroll
        for (int j = 0; j < 8; ++j) acc[i][j] = 0.f;

    for (int k0 = 0; k0 < K; k0 += BK) {
        // ---- load A tile into As[k][m] ----
        if (!TA) {
            // A[M,K]: 128 rows x 16 cols = 512 float4, transpose into LDS
#pragma unroll
            for (int i = 0; i < 2; ++i) {
                int idx = tid + i * 256;
                int m   = idx >> 2;
                int c4  = (idx & 3) * 4;
                const float4 v = *(const float4*)&A[(size_t)(m0 + m) * K + k0 + c4];
                As[c4 + 0][m] = v.x; As[c4 + 1][m] = v.y;
                As[c4 + 2][m] = v.z; As[c4 + 3][m] = v.w;
            }
        } else {
            // A[K,M]: 16 rows x 128 cols, direct float4
#pragma unroll
            for (int i = 0; i < 2; ++i) {
                int idx = tid + i * 256;
                int k   = idx >> 5;
                int c4  = (idx & 31) * 4;
                *(float4*)&As[k][c4] =
                    *(const float4*)&A[(size_t)(k0 + k) * M + m0 + c4];
            }
        }
        // ---- load B tile into Bs[k][n] ----
        if (!TB) {
            // B[K,N]: 16 rows x 128 cols, direct float4
#pragma unroll
            for (int i = 0; i < 2; ++i) {
                int idx = tid + i * 256;
                int k   = idx >> 5;
                int c4  = (idx & 31) * 4;
                *(float4*)&Bs[k][c4] =
                    *(const float4*)&B[(size_t)(k0 + k) * N + n0 + c4];
            }
        } else {
            // B[N,K]: 128 rows x 16 cols, transpose into LDS
#pragma unroll
            for (int i = 0; i < 2; ++i) {
                int idx = tid + i * 256;
                int n   = idx >> 2;
                int c4  = (idx & 3) * 4;
                const float4 v = *(const float4*)&B[(size_t)(n0 + n) * K + k0 + c4];
                Bs[c4 + 0][n] = v.x; Bs[c4 + 1][n] = v.y;
                Bs[c4 + 2][n] = v.z; Bs[c4 + 3][n] = v.w;
            }
        }
        __syncthreads();

#pragma unroll
        for (int kk = 0; kk < BK; ++kk) {
            float a[8], b[8];
            *(float4*)&a[0] = *(const float4*)&As[kk][ty * 4];
            *(float4*)&a[4] = *(const float4*)&As[kk][ty * 4 + 64];
            *(float4*)&b[0] = *(const float4*)&Bs[kk][tx * 4];
            *(float4*)&b[4] = *(const float4*)&Bs[kk][tx * 4 + 64];
#pragma unroll
            for (int i = 0; i < 8; ++i)
#pragma unroll
                for (int j = 0; j < 8; ++j)
                    acc[i][j] = fmaf(a[i], b[j], acc[i][j]);
        }
        __syncthreads();
    }

    // epilogue
    float bj[8];
    if (BIAS_N) {
#pragma unroll
        for (int j = 0; j < 8; ++j)
            bj[j] = bias[n0 + tx * 4 + (j & 3) + (j >> 2) * 64];
    } else {
#pragma unroll
        for (int j = 0; j < 8; ++j) bj[j] = 0.f;
    }
#pragma unroll
    for (int i = 0; i < 8; ++i) {
        int m = m0 + ty * 4 + (i & 3) + (i >> 2) * 64;
        float4 o0, o1;
        o0.x = acc[i][0] + bj[0]; o0.y = acc[i][1] + bj[1];
        o0.z = acc[i][2] + bj[2]; o0.w = acc[i][3] + bj[3];
        o1.x = acc[i][4] + bj[4]; o1.y = acc[i][5] + bj[5];
        o1.z = acc[i][6] + bj[6]; o1.w = acc[i][7] + bj[7];
        *(float4*)&C[(size_t)m * N + n0 + tx * 4]      = o0;
        *(float4*)&C[(size_t)m * N + n0 + tx * 4 + 64] = o1;
    }
}

// ---------------------------------------------------------------------------
// Fused dispatch/combine softmax. One block per token.
// In-place: logits -> D (softmax over p within each group of 32).
// Cb: combine weights (softmax over n, stride 32).
// ---------------------------------------------------------------------------
__global__ __launch_bounds__(256) void softmax_dc(
    float* __restrict__ logits, float* __restrict__ Cb)
{
    __shared__ float ls[NEXP * 33];     // padded: index e + e/32
    __shared__ float dmax[NEXP], dinv[NEXP];
    __shared__ float cmax[PSLOT], cinv[PSLOT];
    const int tid = threadIdx.x;
    const size_t base = (size_t)blockIdx.x * NSLOTS;

#pragma unroll
    for (int i = 0; i < 8; ++i) {
        int e = tid + i * 256;
        ls[e + (e >> 5)] = logits[base + e];
    }
    __syncthreads();

    if (tid < 64) {
        const float* r = &ls[tid * 33];
        float m = r[0];
#pragma unroll
        for (int p = 1; p < PSLOT; ++p) m = fmaxf(m, r[p]);
        float s = 0.f;
#pragma unroll
        for (int p = 0; p < PSLOT; ++p) s += __expf(r[p] - m);
        dmax[tid] = m; dinv[tid] = 1.f / s;
    } else if (tid < 96) {
        int p = tid - 64;
        float m = ls[p];
#pragma unroll
        for (int n = 1; n < NEXP; ++n) m = fmaxf(m, ls[n * 33 + p]);
        float s = 0.f;
#pragma unroll
        for (int n = 0; n < NEXP; ++n) s += __expf(ls[n * 33 + p] - m);
        cmax[p] = m; cinv[p] = 1.f / s;
    }
    __syncthreads();

#pragma unroll
    for (int i = 0; i < 8; ++i) {
        int e = tid + i * 256;
        int n = e >> 5, p = e & 31;
        float l = ls[e + n];
        logits[base + e] = __expf(l - dmax[n]) * dinv[n];
        Cb[base + e]     = __expf(l - cmax[p]) * cinv[p];
    }
}

// ---------------------------------------------------------------------------
// clip -> LayerNorm (no affine) -> tanh, in place. One block per row of 1024.
// ---------------------------------------------------------------------------
__global__ __launch_bounds__(256) void ln_tanh_kernel(float* __restrict__ Xt)
{
    const int tid = threadIdx.x;
    float* row = Xt + (size_t)blockIdx.x * DDIM;
    __shared__ float red1[4], red2[4];

    float4 v = *(float4*)&row[tid * 4];
    v.x = fminf(fmaxf(v.x, -33000.f), 65000.f);
    v.y = fminf(fmaxf(v.y, -33000.f), 65000.f);
    v.z = fminf(fmaxf(v.z, -33000.f), 65000.f);
    v.w = fminf(fmaxf(v.w, -33000.f), 65000.f);

    float s = v.x + v.y + v.z + v.w;
#pragma unroll
    for (int off = 32; off > 0; off >>= 1) s += __shfl_down(s, off);
    if ((tid & 63) == 0) red1[tid >> 6] = s;
    __syncthreads();
    const float mu = (red1[0] + red1[1] + red1[2] + red1[3]) * (1.f / DDIM);

    float dx = v.x - mu, dy = v.y - mu, dz = v.z - mu, dw = v.w - mu;
    float q = dx * dx + dy * dy + dz * dz + dw * dw;
#pragma unroll
    for (int off = 32; off > 0; off >>= 1) q += __shfl_down(q, off);
    if ((tid & 63) == 0) red2[tid >> 6] = q;
    __syncthreads();
    const float var = (red2[0] + red2[1] + red2[2] + red2[3]) * (1.f / DDIM);
    const float sc = rsqrtf(var + LN_EPS);

    float4 o;
    o.x = tanhf(dx * sc); o.y = tanhf(dy * sc);
    o.z = tanhf(dz * sc); o.w = tanhf(dw * sc);
    *(float4*)&row[tid * 4] = o;
}

// ---------------------------------------------------------------------------
// Per-expert GEMM: Yt[n, 0:32, h0:h0+64] = Xt[n] (32x1024) @ W[n] (1024x1024) + b[n]
// grid (HDIM/64, NEXP), 256 threads; thread computes 1 row x 8 cols.
// ---------------------------------------------------------------------------
__global__ __launch_bounds__(256) void expert_gemm(
    const float* __restrict__ Xt, const float* __restrict__ W,
    const float* __restrict__ bias, float* __restrict__ Yt)
{
    const int n  = blockIdx.y;
    const int h0 = blockIdx.x * 64;
    const int tid = threadIdx.x;
    __shared__ float As[32][17];   // [p][k]
    __shared__ float Bs[16][68];   // [k][h]

    const int r  = tid >> 3;         // 0..31
    const int c8 = (tid & 7) * 8;    // 0..56
    float acc[8];
#pragma unroll
    for (int j = 0; j < 8; ++j) acc[j] = 0.f;

    const float* Wn = W + (size_t)n * DDIM * HDIM;
    for (int k0 = 0; k0 < DDIM; k0 += 16) {
        if (tid < 128) {
            int row = tid >> 2, c4 = (tid & 3) * 4;
            const float4 v = *(const float4*)&Xt[(size_t)(n * 32 + row) * DDIM + k0 + c4];
            As[row][c4 + 0] = v.x; As[row][c4 + 1] = v.y;
            As[row][c4 + 2] = v.z; As[row][c4 + 3] = v.w;
        }
        {
            int row = tid >> 4, c4 = (tid & 15) * 4;
            *(float4*)&Bs[row][c4] =
                *(const float4*)&Wn[(size_t)(k0 + row) * HDIM + h0 + c4];
        }
        __syncthreads();
#pragma unroll
        for (int kk = 0; kk < 16; ++kk) {
            float a = As[r][kk];
            const float4 b0 = *(const float4*)&Bs[kk][c8];
            const float4 b1 = *(const float4*)&Bs[kk][c8 + 4];
            acc[0] = fmaf(a, b0.x, acc[0]); acc[1] = fmaf(a, b0.y, acc[1]);
            acc[2] = fmaf(a, b0.z, acc[2]); acc[3] = fmaf(a, b0.w, acc[3]);
            acc[4] = fmaf(a, b1.x, acc[4]); acc[5] = fmaf(a, b1.y, acc[5]);
            acc[6] = fmaf(a, b1.z, acc[6]); acc[7] = fmaf(a, b1.w, acc[7]);
        }
        __syncthreads();
    }

    float4 o0, o1;
    const float* bn = bias + (size_t)n * HDIM + h0 + c8;
    o0.x = acc[0] + bn[0]; o0.y = acc[1] + bn[1];
    o0.z = acc[2] + bn[2]; o0.w = acc[3] + bn[3];
    o1.x = acc[4] + bn[4]; o1.y = acc[5] + bn[5];
    o1.z = acc[6] + bn[6]; o1.w = acc[7] + bn[7];
    float* out = Yt + (size_t)(n * 32 + r) * HDIM + h0 + c8;
    *(float4*)&out[0] = o0;
    *(float4*)&out[4] = o1;
}

// ---------------------------------------------------------------------------
extern "C" void kernel_launch(void* const* d_in, const int* in_sizes, int n_in,
                              void* d_out, int out_size, void* d_ws, size_t ws_size,
                              hipStream_t stream)
{
    const float* x        = (const float*)d_in[0];  // [16384, 1024]
    const float* phi_w    = (const float*)d_in[1];  // [2048, 1024]
    const float* phi_b    = (const float*)d_in[2];  // [2048]
    const float* expert_w = (const float*)d_in[3];  // [64, 1024, 1024]
    const float* expert_b = (const float*)d_in[4];  // [64, 1024]
    float* out = (float*)d_out;                     // [16384, 1024]

    float* logits = (float*)d_ws;                        // 16384*2048 (becomes D)
    float* Cb     = logits + (size_t)TOKENS * NSLOTS;    // 16384*2048
    float* Xt     = Cb + (size_t)TOKENS * NSLOTS;        // 2048*1024
    float* Yt     = Xt + (size_t)NSLOTS * DDIM;          // 2048*1024

    // 1. logits = x @ phi_w^T + phi_b        (NT, bias over N)
    gemm_f32<false, true, true>
        <<<dim3(NSLOTS / 128, TOKENS / 128), 256, 0, stream>>>(
            x, phi_w, phi_b, logits, TOKENS, NSLOTS, DDIM);

    // 2. D (in place) and C softmaxes
    softmax_dc<<<TOKENS, 256, 0, stream>>>(logits, Cb);

    // 3. X_tilde = D^T @ x                   (TN)
    gemm_f32<true, false, false>
        <<<dim3(DDIM / 128, NSLOTS / 128), 256, 0, stream>>>(
            logits, x, nullptr, Xt, NSLOTS, DDIM, TOKENS);

    // 4. clip -> LN -> tanh (in place)
    ln_tanh_kernel<<<NSLOTS, 256, 0, stream>>>(Xt);

    // 5. per-expert linear
    expert_gemm<<<dim3(HDIM / 64, NEXP), 256, 0, stream>>>(
        Xt, expert_w, expert_b, Yt);

    // 6. Y = C @ Y_tilde                     (NN)
    gemm_f32<false, false, false>
        <<<dim3(HDIM / 128, TOKENS / 128), 256, 0, stream>>>(
            Cb, Yt, nullptr, out, TOKENS, HDIM, NSLOTS);
}

// Round 2
// 1109.699 us; speedup vs baseline: 3.7981x; 3.7981x over previous
//
#include <hip/hip_runtime.h>
#include <hip/hip_bf16.h>
#include <math.h>

// Problem constants
#define TOKENS   16384        // T*Z
#define DDIM     1024
#define NEXP     64
#define PSLOT    32
#define NSLOTS   2048         // NEXP*PSLOT
#define HDIM     1024
#define LN_EPS   1e-5f

typedef __bf16 b16x8 __attribute__((ext_vector_type(8)));
typedef float  f32x4 __attribute__((ext_vector_type(4)));

__device__ __forceinline__ unsigned short f2b(float f) {
    union { float f; unsigned u; } v; v.f = f;
    unsigned r = v.u + 0x7FFF + ((v.u >> 16) & 1);   // RNE
    return (unsigned short)(r >> 16);
}

__device__ __forceinline__ void load_lds16(const void* g, void* l) {
    __builtin_amdgcn_global_load_lds(
        (const __attribute__((address_space(1))) void*)g,
        (__attribute__((address_space(3))) void*)l, 16, 0, 0);
}

// ---------------------------------------------------------------------------
// bf16 MFMA GEMM, NT layout: C[M,N] = A[M,K] * B[N,K]^T (+ bias over N)
// 128x128 tile, BK=32, 256 threads = 4 waves (2x2), wave tile 64x64 (4x4 MFMA).
// m97 structure: global_load_lds width-16 staging, single LDS buffer.
// ---------------------------------------------------------------------------
template<bool BIAS>
__global__ __launch_bounds__(256) void gemm_nt_bf16(
    const unsigned short* __restrict__ A,   // [M, K] bf16
    const unsigned short* __restrict__ B,   // [N, K] bf16
    const float* __restrict__ bias,          // [N] or null
    float* __restrict__ C,                   // [M, N]
    int M, int N, int K)
{
    __shared__ unsigned short As[128 * 32];
    __shared__ unsigned short Bs[128 * 32];
    const int tid  = threadIdx.x;
    const int wave = tid >> 6;
    const int lane = tid & 63;
    const int m0 = blockIdx.y * 128;
    const int n0 = blockIdx.x * 128;
    const int wm = (wave >> 1) * 64;
    const int wn = (wave & 1) * 64;

    f32x4 acc[4][4] = {};

    // staging: wave w, issue i -> chunk = w*2+i covers rows [chunk*16, +16)
    // lane: row_in_chunk = lane>>2, k-part = (lane&3)*8  (16 B per lane)
    const int ldrow = lane >> 2;
    const int ldk   = (lane & 3) * 8;

    // fragment read coords (16x16x32 A/B layout: m=lane&15, k=(lane>>4)*8)
    const int fr = lane & 15;
    const int fk = (lane >> 4) * 8;

    for (int k0 = 0; k0 < K; k0 += 32) {
#pragma unroll
        for (int i = 0; i < 2; ++i) {
            const int chunk = wave * 2 + i;
            const int row   = chunk * 16 + ldrow;
            load_lds16(A + (size_t)(m0 + row) * K + k0 + ldk, As + chunk * 512);
            load_lds16(B + (size_t)(n0 + row) * K + k0 + ldk, Bs + chunk * 512);
        }
        __syncthreads();

        b16x8 af[4], bfr[4];
#pragma unroll
        for (int i = 0; i < 4; ++i) {
            af[i]  = *(const b16x8*)&As[(wm + i * 16 + fr) * 32 + fk];
            bfr[i] = *(const b16x8*)&Bs[(wn + i * 16 + fr) * 32 + fk];
        }
#pragma unroll
        for (int i = 0; i < 4; ++i)
#pragma unroll
            for (int j = 0; j < 4; ++j)
                acc[i][j] = __builtin_amdgcn_mfma_f32_16x16x32_bf16(
                    af[i], bfr[j], acc[i][j], 0, 0, 0);
        __syncthreads();
    }

    // epilogue: C/D layout col=lane&15, row=(lane>>4)*4+reg (verified m89/m91)
    const int col  = lane & 15;
    const int row4 = (lane >> 4) * 4;
#pragma unroll
    for (int j = 0; j < 4; ++j) {
        const int n = n0 + wn + j * 16 + col;
        const float bj = BIAS ? bias[n] : 0.f;
#pragma unroll
        for (int i = 0; i < 4; ++i) {
#pragma unroll
            for (int r = 0; r < 4; ++r) {
                const int m = m0 + wm + i * 16 + row4 + r;
                C[(size_t)m * N + n] = acc[i][j][r] + bj;
            }
        }
    }
}

// ---------------------------------------------------------------------------
// elementwise fp32 -> bf16 cast, 8 elems/thread
// ---------------------------------------------------------------------------
__global__ __launch_bounds__(256) void cast_f32_bf16(
    const float* __restrict__ in, unsigned short* __restrict__ out)
{
    const size_t i = (size_t)(blockIdx.x * 256 + threadIdx.x) * 8;
    const float4 a = *(const float4*)&in[i];
    const float4 b = *(const float4*)&in[i + 4];
    ushort4 o0, o1;
    o0.x = f2b(a.x); o0.y = f2b(a.y); o0.z = f2b(a.z); o0.w = f2b(a.w);
    o1.x = f2b(b.x); o1.y = f2b(b.y); o1.z = f2b(b.z); o1.w = f2b(b.w);
    *(ushort4*)&out[i]     = o0;
    *(ushort4*)&out[i + 4] = o1;
}

// ---------------------------------------------------------------------------
// tiled transpose (+cast if fp32 input): in [R,C] -> out [C,R] bf16
// 64x64 tile through LDS.
// ---------------------------------------------------------------------------
template<typename TIN>
__global__ __launch_bounds__(256) void transpose_cast(
    const TIN* __restrict__ in, unsigned short* __restrict__ out, int R, int C)
{
    __shared__ unsigned short tile[64][68];
    const int t  = threadIdx.x;
    const int r0 = blockIdx.y * 64, c0 = blockIdx.x * 64;
    const int tr = t >> 4, tc4 = (t & 15) * 4;
#pragma unroll
    for (int i = 0; i < 4; ++i) {
        const int r = tr + i * 16;
        const TIN* p = in + (size_t)(r0 + r) * C + c0 + tc4;
        if constexpr (sizeof(TIN) == 4) {
            const float4 v = *(const float4*)p;
            tile[tc4 + 0][r] = f2b(v.x); tile[tc4 + 1][r] = f2b(v.y);
            tile[tc4 + 2][r] = f2b(v.z); tile[tc4 + 3][r] = f2b(v.w);
        } else {
            const ushort4 v = *(const ushort4*)p;
            tile[tc4 + 0][r] = v.x; tile[tc4 + 1][r] = v.y;
            tile[tc4 + 2][r] = v.z; tile[tc4 + 3][r] = v.w;
        }
    }
    __syncthreads();
#pragma unroll
    for (int i = 0; i < 4; ++i) {
        const int r = tr + i * 16;
        ushort4 o;
        o.x = tile[r][tc4 + 0]; o.y = tile[r][tc4 + 1];
        o.z = tile[r][tc4 + 2]; o.w = tile[r][tc4 + 3];
        *(ushort4*)&out[(size_t)(c0 + r) * R + r0 + tc4] = o;
    }
}

// ---------------------------------------------------------------------------
// Fused dispatch/combine softmax. One block per token. bf16 outputs.
// ---------------------------------------------------------------------------
__global__ __launch_bounds__(256) void softmax_dc(
    const float* __restrict__ logits,
    unsigned short* __restrict__ Db, unsigned short* __restrict__ Cb)
{
    __shared__ float ls[NEXP * 33];     // padded: index e + e/32
    __shared__ float dmax[NEXP], dinv[NEXP];
    __shared__ float cmax[PSLOT], cinv[PSLOT];
    const int tid = threadIdx.x;
    const size_t base = (size_t)blockIdx.x * NSLOTS;

#pragma unroll
    for (int i = 0; i < 8; ++i) {
        const int e = tid + i * 256;
        ls[e + (e >> 5)] = logits[base + e];
    }
    __syncthreads();

    if (tid < 64) {
        const float* r = &ls[tid * 33];
        float m = r[0];
#pragma unroll
        for (int p = 1; p < PSLOT; ++p) m = fmaxf(m, r[p]);
        float s = 0.f;
#pragma unroll
        for (int p = 0; p < PSLOT; ++p) s += __expf(r[p] - m);
        dmax[tid] = m; dinv[tid] = 1.f / s;
    } else if (tid < 96) {
        const int p = tid - 64;
        float m = ls[p];
#pragma unroll
        for (int n = 1; n < NEXP; ++n) m = fmaxf(m, ls[n * 33 + p]);
        float s = 0.f;
#pragma unroll
        for (int n = 0; n < NEXP; ++n) s += __expf(ls[n * 33 + p] - m);
        cmax[p] = m; cinv[p] = 1.f / s;
    }
    __syncthreads();

#pragma unroll
    for (int i = 0; i < 8; ++i) {
        const int e = tid + i * 256;
        const int n = e >> 5, p = e & 31;
        const float l = ls[e + n];
        Db[base + e] = f2b(__expf(l - dmax[n]) * dinv[n]);
        Cb[base + e] = f2b(__expf(l - cmax[p]) * cinv[p]);
    }
}

// ---------------------------------------------------------------------------
// clip -> LayerNorm (no affine) -> tanh, in place. One block per row of 1024.
// ---------------------------------------------------------------------------
__global__ __launch_bounds__(256) void ln_tanh_kernel(float* __restrict__ Xt)
{
    const int tid = threadIdx.x;
    float* row = Xt + (size_t)blockIdx.x * DDIM;
    __shared__ float red1[4], red2[4];

    float4 v = *(float4*)&row[tid * 4];
    v.x = fminf(fmaxf(v.x, -33000.f), 65000.f);
    v.y = fminf(fmaxf(v.y, -33000.f), 65000.f);
    v.z = fminf(fmaxf(v.z, -33000.f), 65000.f);
    v.w = fminf(fmaxf(v.w, -33000.f), 65000.f);

    float s = v.x + v.y + v.z + v.w;
#pragma unroll
    for (int off = 32; off > 0; off >>= 1) s += __shfl_down(s, off);
    if ((tid & 63) == 0) red1[tid >> 6] = s;
    __syncthreads();
    const float mu = (red1[0] + red1[1] + red1[2] + red1[3]) * (1.f / DDIM);

    const float dx = v.x - mu, dy = v.y - mu, dz = v.z - mu, dw = v.w - mu;
    float q = dx * dx + dy * dy + dz * dz + dw * dw;
#pragma unroll
    for (int off = 32; off > 0; off >>= 1) q += __shfl_down(q, off);
    if ((tid & 63) == 0) red2[tid >> 6] = q;
    __syncthreads();
    const float var = (red2[0] + red2[1] + red2[2] + red2[3]) * (1.f / DDIM);
    const float sc = rsqrtf(var + LN_EPS);

    float4 o;
    o.x = tanhf(dx * sc); o.y = tanhf(dy * sc);
    o.z = tanhf(dz * sc); o.w = tanhf(dw * sc);
    *(float4*)&row[tid * 4] = o;
}

// ---------------------------------------------------------------------------
// Per-expert GEMM (fp32, bound by one-shot 256 MB read of W):
// Yt[n, 0:32, h0:h0+64] = Xt[n] (32x1024) @ W[n] (1024x1024) + b[n]
// ---------------------------------------------------------------------------
__global__ __launch_bounds__(256) void expert_gemm(
    const float* __restrict__ Xt, const float* __restrict__ W,
    const float* __restrict__ bias, float* __restrict__ Yt)
{
    const int n   = blockIdx.y;
    const int h0  = blockIdx.x * 64;
    const int tid = threadIdx.x;
    __shared__ float As[32][17];
    __shared__ float Bs[16][68];

    const int r  = tid >> 3;
    const int c8 = (tid & 7) * 8;
    float acc[8];
#pragma unroll
    for (int j = 0; j < 8; ++j) acc[j] = 0.f;

    const float* Wn = W + (size_t)n * DDIM * HDIM;
    for (int k0 = 0; k0 < DDIM; k0 += 16) {
        if (tid < 128) {
            const int row = tid >> 2, c4 = (tid & 3) * 4;
            const float4 v = *(const float4*)&Xt[(size_t)(n * 32 + row) * DDIM + k0 + c4];
            As[row][c4 + 0] = v.x; As[row][c4 + 1] = v.y;
            As[row][c4 + 2] = v.z; As[row][c4 + 3] = v.w;
        }
        {
            const int row = tid >> 4, c4 = (tid & 15) * 4;
            *(float4*)&Bs[row][c4] =
                *(const float4*)&Wn[(size_t)(k0 + row) * HDIM + h0 + c4];
        }
        __syncthreads();
#pragma unroll
        for (int kk = 0; kk < 16; ++kk) {
            const float a = As[r][kk];
            const float4 b0 = *(const float4*)&Bs[kk][c8];
            const float4 b1 = *(const float4*)&Bs[kk][c8 + 4];
            acc[0] = fmaf(a, b0.x, acc[0]); acc[1] = fmaf(a, b0.y, acc[1]);
            acc[2] = fmaf(a, b0.z, acc[2]); acc[3] = fmaf(a, b0.w, acc[3]);
            acc[4] = fmaf(a, b1.x, acc[4]); acc[5] = fmaf(a, b1.y, acc[5]);
            acc[6] = fmaf(a, b1.z, acc[6]); acc[7] = fmaf(a, b1.w, acc[7]);
        }
        __syncthreads();
    }

    float4 o0, o1;
    const float* bn = bias + (size_t)n * HDIM + h0 + c8;
    o0.x = acc[0] + bn[0]; o0.y = acc[1] + bn[1];
    o0.z = acc[2] + bn[2]; o0.w = acc[3] + bn[3];
    o1.x = acc[4] + bn[4]; o1.y = acc[5] + bn[5];
    o1.z = acc[6] + bn[6]; o1.w = acc[7] + bn[7];
    float* outp = Yt + (size_t)(n * 32 + r) * HDIM + h0 + c8;
    *(float4*)&outp[0] = o0;
    *(float4*)&outp[4] = o1;
}

// ---------------------------------------------------------------------------
extern "C" void kernel_launch(void* const* d_in, const int* in_sizes, int n_in,
                              void* d_out, int out_size, void* d_ws, size_t ws_size,
                              hipStream_t stream)
{
    const float* x        = (const float*)d_in[0];  // [16384, 1024]
    const float* phi_w    = (const float*)d_in[1];  // [2048, 1024]
    const float* phi_b    = (const float*)d_in[2];  // [2048]
    const float* expert_w = (const float*)d_in[3];  // [64, 1024, 1024]
    const float* expert_b = (const float*)d_in[4];  // [64, 1024]
    float* out = (float*)d_out;                     // [16384, 1024]

    char* ws = (char*)d_ws;
    const size_t MB = 1u << 20;
    // region reuse plan (peak 256 MB):
    //  [0,128M):  logits fp32 (gemm1+softmax) -> then xT bf16 @0 (32M) + DbT bf16 @64M (64M)
    //  [128,192M): xb bf16 (32M) + pwb bf16 @160M (4M, gemm1 only)
    //             -> Db bf16 (softmax..transposeD) -> Xt fp32 @128M (8M) + Yt @136M (8M) + YtT @144M (4M)
    //  [192,256M): Cb bf16 (softmax..gemm4)
    float*          logits = (float*)(ws);
    unsigned short* xT     = (unsigned short*)(ws);
    unsigned short* DbT    = (unsigned short*)(ws + 64 * MB);
    unsigned short* xb     = (unsigned short*)(ws + 128 * MB);
    unsigned short* pwb    = (unsigned short*)(ws + 160 * MB);
    unsigned short* Db     = (unsigned short*)(ws + 128 * MB);
    float*          Xt     = (float*)(ws + 128 * MB);
    float*          Yt     = (float*)(ws + 136 * MB);
    unsigned short* YtT    = (unsigned short*)(ws + 144 * MB);
    unsigned short* Cb     = (unsigned short*)(ws + 192 * MB);

    // 0. casts for GEMM1
    cast_f32_bf16<<<TOKENS * DDIM / (256 * 8), 256, 0, stream>>>(x, xb);
    cast_f32_bf16<<<NSLOTS * DDIM / (256 * 8), 256, 0, stream>>>(phi_w, pwb);

    // 1. logits = x @ phi_w^T + phi_b   (MFMA NT)
    gemm_nt_bf16<true><<<dim3(NSLOTS / 128, TOKENS / 128), 256, 0, stream>>>(
        xb, pwb, phi_b, logits, TOKENS, NSLOTS, DDIM);

    // 2. dispatch/combine softmax -> bf16 D, C
    softmax_dc<<<TOKENS, 256, 0, stream>>>(logits, Db, Cb);

    // 3a. xT = x^T bf16 [1024, 16384]   (logits region now dead)
    transpose_cast<float><<<dim3(DDIM / 64, TOKENS / 64), 256, 0, stream>>>(
        x, xT, TOKENS, DDIM);
    // 3b. DbT = D^T bf16 [2048, 16384]
    transpose_cast<unsigned short><<<dim3(NSLOTS / 64, TOKENS / 64), 256, 0, stream>>>(
        Db, DbT, TOKENS, NSLOTS);

    // 3c. X_tilde = D^T @ x   (MFMA NT: A=DbT[2048,16384], B=xT[1024,16384])
    gemm_nt_bf16<false><<<dim3(DDIM / 128, NSLOTS / 128), 256, 0, stream>>>(
        DbT, xT, nullptr, Xt, NSLOTS, DDIM, TOKENS);

    // 4. clip -> LN -> tanh (in place)
    ln_tanh_kernel<<<NSLOTS, 256, 0, stream>>>(Xt);

    // 5. per-expert linear (fp32)
    expert_gemm<<<dim3(HDIM / 64, NEXP), 256, 0, stream>>>(
        Xt, expert_w, expert_b, Yt);

    // 5b. YtT = Yt^T bf16 [1024, 2048]
    transpose_cast<float><<<dim3(HDIM / 64, NSLOTS / 64), 256, 0, stream>>>(
        Yt, YtT, NSLOTS, HDIM);

    // 6. Y = C @ Y_tilde   (MFMA NT: A=Cb[16384,2048], B=YtT[1024,2048])
    gemm_nt_bf16<false><<<dim3(HDIM / 128, TOKENS / 128), 256, 0, stream>>>(
        Cb, YtT, nullptr, out, TOKENS, HDIM, NSLOTS);
}

// Round 3
// 921.276 us; speedup vs baseline: 4.5749x; 1.2045x over previous
//
#include <hip/hip_runtime.h>
#include <hip/hip_bf16.h>
#include <math.h>

// Problem constants
#define TOKENS   16384        // T*Z
#define DDIM     1024
#define NEXP     64
#define PSLOT    32
#define NSLOTS   2048         // NEXP*PSLOT
#define HDIM     1024
#define LN_EPS   1e-5f
#define KSPLIT   8            // split-K factor for GEMM2 (D^T x)

typedef __bf16 b16x8 __attribute__((ext_vector_type(8)));
typedef float  f32x4 __attribute__((ext_vector_type(4)));

__device__ __forceinline__ unsigned short f2b(float f) {
    union { float f; unsigned u; } v; v.f = f;
    unsigned r = v.u + 0x7FFF + ((v.u >> 16) & 1);   // RNE
    return (unsigned short)(r >> 16);
}

__device__ __forceinline__ void load_lds16(const void* g, void* l) {
    __builtin_amdgcn_global_load_lds(
        (const __attribute__((address_space(1))) void*)g,
        (__attribute__((address_space(3))) void*)l, 16, 0, 0);
}

// ---------------------------------------------------------------------------
// bf16 MFMA GEMM, NT layout: C[M,N] = A[M,K] * B[N,K]^T (+ bias over N)
// 128x128 tile, BK=32, 256 threads = 4 waves (2x2), wave tile 64x64 (4x4 MFMA).
// Split-K via gridDim.z: block z covers K-chunk [z*K/S, (z+1)*K/S) and writes
// its partial to C + z*M*N. gridDim.z==1 degenerates to the plain GEMM.
// ---------------------------------------------------------------------------
template<bool BIAS>
__global__ __launch_bounds__(256) void gemm_nt_bf16(
    const unsigned short* __restrict__ A,   // [M, K] bf16
    const unsigned short* __restrict__ B,   // [N, K] bf16
    const float* __restrict__ bias,          // [N] or null
    float* __restrict__ C,                   // [gridDim.z][M, N]
    int M, int N, int K)
{
    __shared__ unsigned short As[128 * 32];
    __shared__ unsigned short Bs[128 * 32];
    const int tid  = threadIdx.x;
    const int wave = tid >> 6;
    const int lane = tid & 63;
    const int m0 = blockIdx.y * 128;
    const int n0 = blockIdx.x * 128;
    const int wm = (wave >> 1) * 64;
    const int wn = (wave & 1) * 64;

    const int kc      = K / gridDim.z;
    const int k_begin = blockIdx.z * kc;
    const int k_end   = k_begin + kc;
    C += (size_t)blockIdx.z * M * N;

    f32x4 acc[4][4] = {};

    // staging: wave w, issue i -> chunk = w*2+i covers rows [chunk*16, +16)
    const int ldrow = lane >> 2;
    const int ldk   = (lane & 3) * 8;
    // fragment read coords (16x16x32 A/B layout: m=lane&15, k=(lane>>4)*8)
    const int fr = lane & 15;
    const int fk = (lane >> 4) * 8;

    for (int k0 = k_begin; k0 < k_end; k0 += 32) {
#pragma unroll
        for (int i = 0; i < 2; ++i) {
            const int chunk = wave * 2 + i;
            const int row   = chunk * 16 + ldrow;
            load_lds16(A + (size_t)(m0 + row) * K + k0 + ldk, As + chunk * 512);
            load_lds16(B + (size_t)(n0 + row) * K + k0 + ldk, Bs + chunk * 512);
        }
        __syncthreads();

        b16x8 af[4], bfr[4];
#pragma unroll
        for (int i = 0; i < 4; ++i) {
            af[i]  = *(const b16x8*)&As[(wm + i * 16 + fr) * 32 + fk];
            bfr[i] = *(const b16x8*)&Bs[(wn + i * 16 + fr) * 32 + fk];
        }
#pragma unroll
        for (int i = 0; i < 4; ++i)
#pragma unroll
            for (int j = 0; j < 4; ++j)
                acc[i][j] = __builtin_amdgcn_mfma_f32_16x16x32_bf16(
                    af[i], bfr[j], acc[i][j], 0, 0, 0);
        __syncthreads();
    }

    // epilogue: C/D layout col=lane&15, row=(lane>>4)*4+reg
    const int col  = lane & 15;
    const int row4 = (lane >> 4) * 4;
#pragma unroll
    for (int j = 0; j < 4; ++j) {
        const int n = n0 + wn + j * 16 + col;
        const float bj = BIAS ? bias[n] : 0.f;
#pragma unroll
        for (int i = 0; i < 4; ++i) {
#pragma unroll
            for (int r = 0; r < 4; ++r) {
                const int m = m0 + wm + i * 16 + row4 + r;
                C[(size_t)m * N + n] = acc[i][j][r] + bj;
            }
        }
    }
}

// ---------------------------------------------------------------------------
// elementwise fp32 -> bf16 cast, 8 elems/thread
// ---------------------------------------------------------------------------
__global__ __launch_bounds__(256) void cast_f32_bf16(
    const float* __restrict__ in, unsigned short* __restrict__ out)
{
    const size_t i = (size_t)(blockIdx.x * 256 + threadIdx.x) * 8;
    const float4 a = *(const float4*)&in[i];
    const float4 b = *(const float4*)&in[i + 4];
    ushort4 o0, o1;
    o0.x = f2b(a.x); o0.y = f2b(a.y); o0.z = f2b(a.z); o0.w = f2b(a.w);
    o1.x = f2b(b.x); o1.y = f2b(b.y); o1.z = f2b(b.z); o1.w = f2b(b.w);
    *(ushort4*)&out[i]     = o0;
    *(ushort4*)&out[i + 4] = o1;
}

// ---------------------------------------------------------------------------
// tiled transpose (+cast if fp32 input): in [R,C] -> out [C,R] bf16
// ---------------------------------------------------------------------------
template<typename TIN>
__global__ __launch_bounds__(256) void transpose_cast(
    const TIN* __restrict__ in, unsigned short* __restrict__ out, int R, int C)
{
    __shared__ unsigned short tile[64][68];
    const int t  = threadIdx.x;
    const int r0 = blockIdx.y * 64, c0 = blockIdx.x * 64;
    const int tr = t >> 4, tc4 = (t & 15) * 4;
#pragma unroll
    for (int i = 0; i < 4; ++i) {
        const int r = tr + i * 16;
        const TIN* p = in + (size_t)(r0 + r) * C + c0 + tc4;
        if constexpr (sizeof(TIN) == 4) {
            const float4 v = *(const float4*)p;
            tile[tc4 + 0][r] = f2b(v.x); tile[tc4 + 1][r] = f2b(v.y);
            tile[tc4 + 2][r] = f2b(v.z); tile[tc4 + 3][r] = f2b(v.w);
        } else {
            const ushort4 v = *(const ushort4*)p;
            tile[tc4 + 0][r] = v.x; tile[tc4 + 1][r] = v.y;
            tile[tc4 + 2][r] = v.z; tile[tc4 + 3][r] = v.w;
        }
    }
    __syncthreads();
#pragma unroll
    for (int i = 0; i < 4; ++i) {
        const int r = tr + i * 16;
        ushort4 o;
        o.x = tile[r][tc4 + 0]; o.y = tile[r][tc4 + 1];
        o.z = tile[r][tc4 + 2]; o.w = tile[r][tc4 + 3];
        *(ushort4*)&out[(size_t)(c0 + r) * R + r0 + tc4] = o;
    }
}

// ---------------------------------------------------------------------------
// Fused dispatch/combine softmax. One block per token. bf16 outputs.
// ---------------------------------------------------------------------------
__global__ __launch_bounds__(256) void softmax_dc(
    const float* __restrict__ logits,
    unsigned short* __restrict__ Db, unsigned short* __restrict__ Cb)
{
    __shared__ float ls[NEXP * 33];     // padded: index e + e/32
    __shared__ float dmax[NEXP], dinv[NEXP];
    __shared__ float cmax[PSLOT], cinv[PSLOT];
    const int tid = threadIdx.x;
    const size_t base = (size_t)blockIdx.x * NSLOTS;

#pragma unroll
    for (int i = 0; i < 8; ++i) {
        const int e = tid + i * 256;
        ls[e + (e >> 5)] = logits[base + e];
    }
    __syncthreads();

    if (tid < 64) {
        const float* r = &ls[tid * 33];
        float m = r[0];
#pragma unroll
        for (int p = 1; p < PSLOT; ++p) m = fmaxf(m, r[p]);
        float s = 0.f;
#pragma unroll
        for (int p = 0; p < PSLOT; ++p) s += __expf(r[p] - m);
        dmax[tid] = m; dinv[tid] = 1.f / s;
    } else if (tid < 96) {
        const int p = tid - 64;
        float m = ls[p];
#pragma unroll
        for (int n = 1; n < NEXP; ++n) m = fmaxf(m, ls[n * 33 + p]);
        float s = 0.f;
#pragma unroll
        for (int n = 0; n < NEXP; ++n) s += __expf(ls[n * 33 + p] - m);
        cmax[p] = m; cinv[p] = 1.f / s;
    }
    __syncthreads();

#pragma unroll
    for (int i = 0; i < 8; ++i) {
        const int e = tid + i * 256;
        const int n = e >> 5, p = e & 31;
        const float l = ls[e + n];
        Db[base + e] = f2b(__expf(l - dmax[n]) * dinv[n]);
        Cb[base + e] = f2b(__expf(l - cmax[p]) * cinv[p]);
    }
}

// ---------------------------------------------------------------------------
// split-K reduce -> clip -> LayerNorm -> tanh. One block per slot row.
// parts: [KSPLIT][NSLOTS*DDIM] fp32 partials from GEMM2.
// ---------------------------------------------------------------------------
__global__ __launch_bounds__(256) void reduce_ln_tanh(
    const float* __restrict__ parts, float* __restrict__ Xt)
{
    const int tid = threadIdx.x;
    const size_t off = (size_t)blockIdx.x * DDIM + tid * 4;
    __shared__ float red1[4], red2[4];

    float4 v = *(const float4*)&parts[off];
#pragma unroll
    for (int s = 1; s < KSPLIT; ++s) {
        const float4 p = *(const float4*)&parts[(size_t)s * NSLOTS * DDIM + off];
        v.x += p.x; v.y += p.y; v.z += p.z; v.w += p.w;
    }
    v.x = fminf(fmaxf(v.x, -33000.f), 65000.f);
    v.y = fminf(fmaxf(v.y, -33000.f), 65000.f);
    v.z = fminf(fmaxf(v.z, -33000.f), 65000.f);
    v.w = fminf(fmaxf(v.w, -33000.f), 65000.f);

    float s = v.x + v.y + v.z + v.w;
#pragma unroll
    for (int off2 = 32; off2 > 0; off2 >>= 1) s += __shfl_down(s, off2);
    if ((tid & 63) == 0) red1[tid >> 6] = s;
    __syncthreads();
    const float mu = (red1[0] + red1[1] + red1[2] + red1[3]) * (1.f / DDIM);

    const float dx = v.x - mu, dy = v.y - mu, dz = v.z - mu, dw = v.w - mu;
    float q = dx * dx + dy * dy + dz * dz + dw * dw;
#pragma unroll
    for (int off2 = 32; off2 > 0; off2 >>= 1) q += __shfl_down(q, off2);
    if ((tid & 63) == 0) red2[tid >> 6] = q;
    __syncthreads();
    const float var = (red2[0] + red2[1] + red2[2] + red2[3]) * (1.f / DDIM);
    const float sc = rsqrtf(var + LN_EPS);

    float4 o;
    o.x = tanhf(dx * sc); o.y = tanhf(dy * sc);
    o.z = tanhf(dz * sc); o.w = tanhf(dw * sc);
    *(float4*)&Xt[off] = o;
}

// ---------------------------------------------------------------------------
// Per-expert GEMM (fp32, bound by one-shot 256 MB read of W):
// Yt[n, 0:32, h0:h0+64] = Xt[n] (32x1024) @ W[n] (1024x1024) + b[n]
// ---------------------------------------------------------------------------
__global__ __launch_bounds__(256) void expert_gemm(
    const float* __restrict__ Xt, const float* __restrict__ W,
    const float* __restrict__ bias, float* __restrict__ Yt)
{
    const int n   = blockIdx.y;
    const int h0  = blockIdx.x * 64;
    const int tid = threadIdx.x;
    __shared__ float As[32][17];
    __shared__ float Bs[16][68];

    const int r  = tid >> 3;
    const int c8 = (tid & 7) * 8;
    float acc[8];
#pragma unroll
    for (int j = 0; j < 8; ++j) acc[j] = 0.f;

    const float* Wn = W + (size_t)n * DDIM * HDIM;
    for (int k0 = 0; k0 < DDIM; k0 += 16) {
        if (tid < 128) {
            const int row = tid >> 2, c4 = (tid & 3) * 4;
            const float4 v = *(const float4*)&Xt[(size_t)(n * 32 + row) * DDIM + k0 + c4];
            As[row][c4 + 0] = v.x; As[row][c4 + 1] = v.y;
            As[row][c4 + 2] = v.z; As[row][c4 + 3] = v.w;
        }
        {
            const int row = tid >> 4, c4 = (tid & 15) * 4;
            *(float4*)&Bs[row][c4] =
                *(const float4*)&Wn[(size_t)(k0 + row) * HDIM + h0 + c4];
        }
        __syncthreads();
#pragma unroll
        for (int kk = 0; kk < 16; ++kk) {
            const float a = As[r][kk];
            const float4 b0 = *(const float4*)&Bs[kk][c8];
            const float4 b1 = *(const float4*)&Bs[kk][c8 + 4];
            acc[0] = fmaf(a, b0.x, acc[0]); acc[1] = fmaf(a, b0.y, acc[1]);
            acc[2] = fmaf(a, b0.z, acc[2]); acc[3] = fmaf(a, b0.w, acc[3]);
            acc[4] = fmaf(a, b1.x, acc[4]); acc[5] = fmaf(a, b1.y, acc[5]);
            acc[6] = fmaf(a, b1.z, acc[6]); acc[7] = fmaf(a, b1.w, acc[7]);
        }
        __syncthreads();
    }

    float4 o0, o1;
    const float* bn = bias + (size_t)n * HDIM + h0 + c8;
    o0.x = acc[0] + bn[0]; o0.y = acc[1] + bn[1];
    o0.z = acc[2] + bn[2]; o0.w = acc[3] + bn[3];
    o1.x = acc[4] + bn[4]; o1.y = acc[5] + bn[5];
    o1.z = acc[6] + bn[6]; o1.w = acc[7] + bn[7];
    float* outp = Yt + (size_t)(n * 32 + r) * HDIM + h0 + c8;
    *(float4*)&outp[0] = o0;
    *(float4*)&outp[4] = o1;
}

// ---------------------------------------------------------------------------
extern "C" void kernel_launch(void* const* d_in, const int* in_sizes, int n_in,
                              void* d_out, int out_size, void* d_ws, size_t ws_size,
                              hipStream_t stream)
{
    const float* x        = (const float*)d_in[0];  // [16384, 1024]
    const float* phi_w    = (const float*)d_in[1];  // [2048, 1024]
    const float* phi_b    = (const float*)d_in[2];  // [2048]
    const float* expert_w = (const float*)d_in[3];  // [64, 1024, 1024]
    const float* expert_b = (const float*)d_in[4];  // [64, 1024]
    float* out = (float*)d_out;                     // [16384, 1024]

    char* ws = (char*)d_ws;
    const size_t MB = 1u << 20;
    // Buffer lifetime plan (peak 256 MB; 272 MB proven available):
    //  phase 1 (gemm1):   logits[0,128M) | xb[128,160M) pwb[160,164M)
    //  phase 2 (softmax): logits[0,128M) | Db[128,192M) Cb[192,256M)
    //  phase 3 (transp):  xT[0,32M) DbT[32,96M) | Db dying | Cb
    //  phase 4 (gemm2):   parts[96,160M) (8x8MB, overwrites dead Db) | Cb
    //  phase 5 (tail):    Xt[160,168M) Yt[168,176M) YtT[176,180M) | Cb
    float*          logits = (float*)(ws);
    unsigned short* xb     = (unsigned short*)(ws + 128 * MB);
    unsigned short* pwb    = (unsigned short*)(ws + 160 * MB);
    unsigned short* Db     = (unsigned short*)(ws + 128 * MB);
    unsigned short* Cb     = (unsigned short*)(ws + 192 * MB);
    unsigned short* xT     = (unsigned short*)(ws);
    unsigned short* DbT    = (unsigned short*)(ws + 32 * MB);
    float*          parts  = (float*)(ws + 96 * MB);
    float*          Xt     = (float*)(ws + 160 * MB);
    float*          Yt     = (float*)(ws + 168 * MB);
    unsigned short* YtT    = (unsigned short*)(ws + 176 * MB);

    // 0. casts for GEMM1
    cast_f32_bf16<<<TOKENS * DDIM / (256 * 8), 256, 0, stream>>>(x, xb);
    cast_f32_bf16<<<NSLOTS * DDIM / (256 * 8), 256, 0, stream>>>(phi_w, pwb);

    // 1. logits = x @ phi_w^T + phi_b   (MFMA NT, 2048 blocks)
    gemm_nt_bf16<true><<<dim3(NSLOTS / 128, TOKENS / 128), 256, 0, stream>>>(
        xb, pwb, phi_b, logits, TOKENS, NSLOTS, DDIM);

    // 2. dispatch/combine softmax -> bf16 D, C
    softmax_dc<<<TOKENS, 256, 0, stream>>>(logits, Db, Cb);

    // 3a. xT = x^T bf16 [1024, 16384]
    transpose_cast<float><<<dim3(DDIM / 64, TOKENS / 64), 256, 0, stream>>>(
        x, xT, TOKENS, DDIM);
    // 3b. DbT = D^T bf16 [2048, 16384]
    transpose_cast<unsigned short><<<dim3(NSLOTS / 64, TOKENS / 64), 256, 0, stream>>>(
        Db, DbT, TOKENS, NSLOTS);

    // 3c. X_tilde partials = D^T @ x, split-K 8 (1024 blocks)
    gemm_nt_bf16<false>
        <<<dim3(DDIM / 128, NSLOTS / 128, KSPLIT), 256, 0, stream>>>(
            DbT, xT, nullptr, parts, NSLOTS, DDIM, TOKENS);

    // 4. reduce splits -> clip -> LN -> tanh
    reduce_ln_tanh<<<NSLOTS, 256, 0, stream>>>(parts, Xt);

    // 5. per-expert linear (fp32)
    expert_gemm<<<dim3(HDIM / 64, NEXP), 256, 0, stream>>>(
        Xt, expert_w, expert_b, Yt);

    // 5b. YtT = Yt^T bf16 [1024, 2048]
    transpose_cast<float><<<dim3(HDIM / 64, NSLOTS / 64), 256, 0, stream>>>(
        Yt, YtT, NSLOTS, HDIM);

    // 6. Y = C @ Y_tilde   (MFMA NT, 1024 blocks)
    gemm_nt_bf16<false><<<dim3(HDIM / 128, TOKENS / 128), 256, 0, stream>>>(
        Cb, YtT, nullptr, out, TOKENS, HDIM, NSLOTS);
}

// Round 4
// 897.844 us; speedup vs baseline: 4.6943x; 1.0261x over previous
//
#include <hip/hip_runtime.h>
#include <hip/hip_bf16.h>
#include <math.h>

// Problem constants
#define TOKENS   16384        // T*Z
#define DDIM     1024
#define NEXP     64
#define PSLOT    32
#define NSLOTS   2048         // NEXP*PSLOT
#define HDIM     1024
#define LN_EPS   1e-5f
#define KSPLIT   8            // split-K factor for GEMM2 (D^T x)

typedef __bf16 b16x8 __attribute__((ext_vector_type(8)));
typedef float  f32x4 __attribute__((ext_vector_type(4)));

__device__ __forceinline__ unsigned short f2b(float f) {
    union { float f; unsigned u; } v; v.f = f;
    unsigned r = v.u + 0x7FFF + ((v.u >> 16) & 1);   // RNE
    return (unsigned short)(r >> 16);
}

__device__ __forceinline__ void load_lds16(const void* g, void* l) {
    __builtin_amdgcn_global_load_lds(
        (const __attribute__((address_space(1))) void*)g,
        (__attribute__((address_space(3))) void*)l, 16, 0, 0);
}

// ---------------------------------------------------------------------------
// bf16 MFMA GEMM, NT layout: C[M,N] = A[M,K] * B[N,K]^T (+ bias over N)
// 128x128 tile, BK=64 (one barrier per 32 MFMAs), 256 threads = 4 waves (2x2),
// wave tile 64x64 (4x4 MFMA 16x16x32). XOR k-slot swizzle in the staging
// address keeps fragment ds_read_b128 spread over 8 banks (row stride 128 B).
// Split-K via gridDim.z: block z covers [z*K/S,(z+1)*K/S), partial -> C+z*M*N.
// ---------------------------------------------------------------------------
template<bool BIAS>
__global__ __launch_bounds__(256) void gemm_nt_bf16(
    const unsigned short* __restrict__ A,   // [M, K] bf16
    const unsigned short* __restrict__ B,   // [N, K] bf16
    const float* __restrict__ bias,          // [N] or null
    float* __restrict__ C,                   // [gridDim.z][M, N]
    int M, int N, int K)
{
    __shared__ unsigned short As[128 * 64];   // [row][kslot*8], kslot swizzled
    __shared__ unsigned short Bs[128 * 64];
    const int tid  = threadIdx.x;
    const int wave = tid >> 6;
    const int lane = tid & 63;
    const int m0 = blockIdx.y * 128;
    const int n0 = blockIdx.x * 128;
    const int wm = (wave >> 1) * 64;
    const int wn = (wave & 1) * 64;

    const int kc      = K / gridDim.z;
    const int k_begin = blockIdx.z * kc;
    const int k_end   = k_begin + kc;
    C += (size_t)blockIdx.z * M * N;

    f32x4 acc[4][4] = {};

    // staging: issue i of wave w covers rows [(w*4+i)*8, +8); lane L:
    // row_in_chunk = L>>3, kslot = L&7, swizzled global k = (kslot ^ (row&7))*8
    const int ldrow = lane >> 3;
    const int ldko  = ((lane & 7) ^ (ldrow & 7)) * 8;
    // fragment read coords: m = wm/wn + i*16 + fr; k-slot s = h*4 + (lane>>4),
    // stored at column s ^ (m&7)
    const int fr = lane & 15;
    const int fs = lane >> 4;        // 0..3

    for (int k0 = k_begin; k0 < k_end; k0 += 64) {
#pragma unroll
        for (int i = 0; i < 4; ++i) {
            const int chunk = wave * 4 + i;           // 0..15
            const int row   = chunk * 8 + ldrow;      // 0..127
            load_lds16(A + (size_t)(m0 + row) * K + k0 + ldko, As + chunk * 512);
            load_lds16(B + (size_t)(n0 + row) * K + k0 + ldko, Bs + chunk * 512);
        }
        __syncthreads();

#pragma unroll
        for (int h = 0; h < 2; ++h) {
            const int s = h * 4 + fs;
            b16x8 af[4], bfr[4];
#pragma unroll
            for (int i = 0; i < 4; ++i) {
                const int ma = wm + i * 16 + fr;
                const int mb = wn + i * 16 + fr;
                af[i]  = *(const b16x8*)&As[ma * 64 + (s ^ (ma & 7)) * 8];
                bfr[i] = *(const b16x8*)&Bs[mb * 64 + (s ^ (mb & 7)) * 8];
            }
#pragma unroll
            for (int i = 0; i < 4; ++i)
#pragma unroll
                for (int j = 0; j < 4; ++j)
                    acc[i][j] = __builtin_amdgcn_mfma_f32_16x16x32_bf16(
                        af[i], bfr[j], acc[i][j], 0, 0, 0);
        }
        __syncthreads();
    }

    // epilogue: C/D layout col=lane&15, row=(lane>>4)*4+reg
    const int col  = lane & 15;
    const int row4 = (lane >> 4) * 4;
#pragma unroll
    for (int j = 0; j < 4; ++j) {
        const int n = n0 + wn + j * 16 + col;
        const float bj = BIAS ? bias[n] : 0.f;
#pragma unroll
        for (int i = 0; i < 4; ++i) {
#pragma unroll
            for (int r = 0; r < 4; ++r) {
                const int m = m0 + wm + i * 16 + row4 + r;
                C[(size_t)m * N + n] = acc[i][j][r] + bj;
            }
        }
    }
}

// ---------------------------------------------------------------------------
// prep_x: one pass over x producing xb (bf16, same layout) and xT (bf16,
// transposed). 64x64 tile through LDS.
// ---------------------------------------------------------------------------
__global__ __launch_bounds__(256) void prep_x(
    const float* __restrict__ in, unsigned short* __restrict__ xb,
    unsigned short* __restrict__ xT)
{
    __shared__ unsigned short tile[64][68];
    const int t  = threadIdx.x;
    const int c0 = blockIdx.x * 64;   // d
    const int r0 = blockIdx.y * 64;   // token
    const int tr = t >> 4, tc4 = (t & 15) * 4;
#pragma unroll
    for (int i = 0; i < 4; ++i) {
        const int r = tr + i * 16;
        const float4 v = *(const float4*)&in[(size_t)(r0 + r) * DDIM + c0 + tc4];
        ushort4 o;
        o.x = f2b(v.x); o.y = f2b(v.y); o.z = f2b(v.z); o.w = f2b(v.w);
        *(ushort4*)&xb[(size_t)(r0 + r) * DDIM + c0 + tc4] = o;
        tile[tc4 + 0][r] = o.x; tile[tc4 + 1][r] = o.y;
        tile[tc4 + 2][r] = o.z; tile[tc4 + 3][r] = o.w;
    }
    __syncthreads();
#pragma unroll
    for (int i = 0; i < 4; ++i) {
        const int r = tr + i * 16;
        ushort4 o;
        o.x = tile[r][tc4 + 0]; o.y = tile[r][tc4 + 1];
        o.z = tile[r][tc4 + 2]; o.w = tile[r][tc4 + 3];
        *(ushort4*)&xT[(size_t)(c0 + r) * TOKENS + r0 + tc4] = o;
    }
}

// ---------------------------------------------------------------------------
// elementwise fp32 -> bf16 cast, 8 elems/thread (phi_w only)
// ---------------------------------------------------------------------------
__global__ __launch_bounds__(256) void cast_f32_bf16(
    const float* __restrict__ in, unsigned short* __restrict__ out)
{
    const size_t i = (size_t)(blockIdx.x * 256 + threadIdx.x) * 8;
    const float4 a = *(const float4*)&in[i];
    const float4 b = *(const float4*)&in[i + 4];
    ushort4 o0, o1;
    o0.x = f2b(a.x); o0.y = f2b(a.y); o0.z = f2b(a.z); o0.w = f2b(a.w);
    o1.x = f2b(b.x); o1.y = f2b(b.y); o1.z = f2b(b.z); o1.w = f2b(b.w);
    *(ushort4*)&out[i]     = o0;
    *(ushort4*)&out[i + 4] = o1;
}

// ---------------------------------------------------------------------------
// tiled transpose bf16 -> bf16 / fp32 -> bf16: in [R,C] -> out [C,R]
// ---------------------------------------------------------------------------
template<typename TIN>
__global__ __launch_bounds__(256) void transpose_cast(
    const TIN* __restrict__ in, unsigned short* __restrict__ out, int R, int C)
{
    __shared__ unsigned short tile[64][68];
    const int t  = threadIdx.x;
    const int r0 = blockIdx.y * 64, c0 = blockIdx.x * 64;
    const int tr = t >> 4, tc4 = (t & 15) * 4;
#pragma unroll
    for (int i = 0; i < 4; ++i) {
        const int r = tr + i * 16;
        const TIN* p = in + (size_t)(r0 + r) * C + c0 + tc4;
        if constexpr (sizeof(TIN) == 4) {
            const float4 v = *(const float4*)p;
            tile[tc4 + 0][r] = f2b(v.x); tile[tc4 + 1][r] = f2b(v.y);
            tile[tc4 + 2][r] = f2b(v.z); tile[tc4 + 3][r] = f2b(v.w);
        } else {
            const ushort4 v = *(const ushort4*)p;
            tile[tc4 + 0][r] = v.x; tile[tc4 + 1][r] = v.y;
            tile[tc4 + 2][r] = v.z; tile[tc4 + 3][r] = v.w;
        }
    }
    __syncthreads();
#pragma unroll
    for (int i = 0; i < 4; ++i) {
        const int r = tr + i * 16;
        ushort4 o;
        o.x = tile[r][tc4 + 0]; o.y = tile[r][tc4 + 1];
        o.z = tile[r][tc4 + 2]; o.w = tile[r][tc4 + 3];
        *(ushort4*)&out[(size_t)(c0 + r) * R + r0 + tc4] = o;
    }
}

// ---------------------------------------------------------------------------
// Fused dispatch/combine softmax. One block per token. bf16 outputs.
// ---------------------------------------------------------------------------
__global__ __launch_bounds__(256) void softmax_dc(
    const float* __restrict__ logits,
    unsigned short* __restrict__ Db, unsigned short* __restrict__ Cb)
{
    __shared__ float ls[NEXP * 33];     // padded: index e + e/32
    __shared__ float dmax[NEXP], dinv[NEXP];
    __shared__ float cmax[PSLOT], cinv[PSLOT];
    const int tid = threadIdx.x;
    const size_t base = (size_t)blockIdx.x * NSLOTS;

#pragma unroll
    for (int i = 0; i < 8; ++i) {
        const int e = tid + i * 256;
        ls[e + (e >> 5)] = logits[base + e];
    }
    __syncthreads();

    if (tid < 64) {
        const float* r = &ls[tid * 33];
        float m = r[0];
#pragma unroll
        for (int p = 1; p < PSLOT; ++p) m = fmaxf(m, r[p]);
        float s = 0.f;
#pragma unroll
        for (int p = 0; p < PSLOT; ++p) s += __expf(r[p] - m);
        dmax[tid] = m; dinv[tid] = 1.f / s;
    } else if (tid < 96) {
        const int p = tid - 64;
        float m = ls[p];
#pragma unroll
        for (int n = 1; n < NEXP; ++n) m = fmaxf(m, ls[n * 33 + p]);
        float s = 0.f;
#pragma unroll
        for (int n = 0; n < NEXP; ++n) s += __expf(ls[n * 33 + p] - m);
        cmax[p] = m; cinv[p] = 1.f / s;
    }
    __syncthreads();

#pragma unroll
    for (int i = 0; i < 8; ++i) {
        const int e = tid + i * 256;
        const int n = e >> 5, p = e & 31;
        const float l = ls[e + n];
        Db[base + e] = f2b(__expf(l - dmax[n]) * dinv[n]);
        Cb[base + e] = f2b(__expf(l - cmax[p]) * cinv[p]);
    }
}

// ---------------------------------------------------------------------------
// split-K reduce -> clip -> LayerNorm -> tanh. One block per slot row.
// ---------------------------------------------------------------------------
__global__ __launch_bounds__(256) void reduce_ln_tanh(
    const float* __restrict__ parts, float* __restrict__ Xt)
{
    const int tid = threadIdx.x;
    const size_t off = (size_t)blockIdx.x * DDIM + tid * 4;
    __shared__ float red1[4], red2[4];

    float4 v = *(const float4*)&parts[off];
#pragma unroll
    for (int s = 1; s < KSPLIT; ++s) {
        const float4 p = *(const float4*)&parts[(size_t)s * NSLOTS * DDIM + off];
        v.x += p.x; v.y += p.y; v.z += p.z; v.w += p.w;
    }
    v.x = fminf(fmaxf(v.x, -33000.f), 65000.f);
    v.y = fminf(fmaxf(v.y, -33000.f), 65000.f);
    v.z = fminf(fmaxf(v.z, -33000.f), 65000.f);
    v.w = fminf(fmaxf(v.w, -33000.f), 65000.f);

    float s = v.x + v.y + v.z + v.w;
#pragma unroll
    for (int off2 = 32; off2 > 0; off2 >>= 1) s += __shfl_down(s, off2);
    if ((tid & 63) == 0) red1[tid >> 6] = s;
    __syncthreads();
    const float mu = (red1[0] + red1[1] + red1[2] + red1[3]) * (1.f / DDIM);

    const float dx = v.x - mu, dy = v.y - mu, dz = v.z - mu, dw = v.w - mu;
    float q = dx * dx + dy * dy + dz * dz + dw * dw;
#pragma unroll
    for (int off2 = 32; off2 > 0; off2 >>= 1) q += __shfl_down(q, off2);
    if ((tid & 63) == 0) red2[tid >> 6] = q;
    __syncthreads();
    const float var = (red2[0] + red2[1] + red2[2] + red2[3]) * (1.f / DDIM);
    const float sc = rsqrtf(var + LN_EPS);

    float4 o;
    o.x = tanhf(dx * sc); o.y = tanhf(dy * sc);
    o.z = tanhf(dz * sc); o.w = tanhf(dw * sc);
    *(float4*)&Xt[off] = o;
}

// ---------------------------------------------------------------------------
// Per-expert GEMM (fp32, HBM-bound on one-shot 256 MB read of W):
// Yt[n, 0:32, h0:h0+64] = Xt[n] (32x1024) @ W[n] (1024x1024) + b[n]
// ---------------------------------------------------------------------------
__global__ __launch_bounds__(256) void expert_gemm(
    const float* __restrict__ Xt, const float* __restrict__ W,
    const float* __restrict__ bias, float* __restrict__ Yt)
{
    const int n   = blockIdx.y;
    const int h0  = blockIdx.x * 64;
    const int tid = threadIdx.x;
    __shared__ float As[32][17];
    __shared__ float Bs[16][68];

    const int r  = tid >> 3;
    const int c8 = (tid & 7) * 8;
    float acc[8];
#pragma unroll
    for (int j = 0; j < 8; ++j) acc[j] = 0.f;

    const float* Wn = W + (size_t)n * DDIM * HDIM;
    for (int k0 = 0; k0 < DDIM; k0 += 16) {
        if (tid < 128) {
            const int row = tid >> 2, c4 = (tid & 3) * 4;
            const float4 v = *(const float4*)&Xt[(size_t)(n * 32 + row) * DDIM + k0 + c4];
            As[row][c4 + 0] = v.x; As[row][c4 + 1] = v.y;
            As[row][c4 + 2] = v.z; As[row][c4 + 3] = v.w;
        }
        {
            const int row = tid >> 4, c4 = (tid & 15) * 4;
            *(float4*)&Bs[row][c4] =
                *(const float4*)&Wn[(size_t)(k0 + row) * HDIM + h0 + c4];
        }
        __syncthreads();
#pragma unroll
        for (int kk = 0; kk < 16; ++kk) {
            const float a = As[r][kk];
            const float4 b0 = *(const float4*)&Bs[kk][c8];
            const float4 b1 = *(const float4*)&Bs[kk][c8 + 4];
            acc[0] = fmaf(a, b0.x, acc[0]); acc[1] = fmaf(a, b0.y, acc[1]);
            acc[2] = fmaf(a, b0.z, acc[2]); acc[3] = fmaf(a, b0.w, acc[3]);
            acc[4] = fmaf(a, b1.x, acc[4]); acc[5] = fmaf(a, b1.y, acc[5]);
            acc[6] = fmaf(a, b1.z, acc[6]); acc[7] = fmaf(a, b1.w, acc[7]);
        }
        __syncthreads();
    }

    float4 o0, o1;
    const float* bn = bias + (size_t)n * HDIM + h0 + c8;
    o0.x = acc[0] + bn[0]; o0.y = acc[1] + bn[1];
    o0.z = acc[2] + bn[2]; o0.w = acc[3] + bn[3];
    o1.x = acc[4] + bn[4]; o1.y = acc[5] + bn[5];
    o1.z = acc[6] + bn[6]; o1.w = acc[7] + bn[7];
    float* outp = Yt + (size_t)(n * 32 + r) * HDIM + h0 + c8;
    *(float4*)&outp[0] = o0;
    *(float4*)&outp[4] = o1;
}

// ---------------------------------------------------------------------------
extern "C" void kernel_launch(void* const* d_in, const int* in_sizes, int n_in,
                              void* d_out, int out_size, void* d_ws, size_t ws_size,
                              hipStream_t stream)
{
    const float* x        = (const float*)d_in[0];  // [16384, 1024]
    const float* phi_w    = (const float*)d_in[1];  // [2048, 1024]
    const float* phi_b    = (const float*)d_in[2];  // [2048]
    const float* expert_w = (const float*)d_in[3];  // [64, 1024, 1024]
    const float* expert_b = (const float*)d_in[4];  // [64, 1024]
    float* out = (float*)d_out;                     // [16384, 1024]

    char* ws = (char*)d_ws;
    const size_t MB = 1u << 20;
    // ws_size = 1 GB (fill dispatch wrote 1.074e9 B) -> disjoint layout, 472 MB
    unsigned short* xb     = (unsigned short*)(ws);              // 32 MB
    unsigned short* xT     = (unsigned short*)(ws +  32 * MB);   // 32 MB
    unsigned short* pwb    = (unsigned short*)(ws +  64 * MB);   //  4 MB
    float*          logits = (float*)(ws +  68 * MB);            // 128 MB
    unsigned short* Db     = (unsigned short*)(ws + 196 * MB);   // 64 MB
    unsigned short* Cb     = (unsigned short*)(ws + 260 * MB);   // 64 MB
    unsigned short* DbT    = (unsigned short*)(ws + 324 * MB);   // 64 MB
    float*          parts  = (float*)(ws + 388 * MB);            // 64 MB
    float*          Xt     = (float*)(ws + 452 * MB);            //  8 MB
    float*          Yt     = (float*)(ws + 460 * MB);            //  8 MB
    unsigned short* YtT    = (unsigned short*)(ws + 468 * MB);   //  4 MB

    // 0. prep: x -> xb + xT (one read), phi_w -> bf16
    prep_x<<<dim3(DDIM / 64, TOKENS / 64), 256, 0, stream>>>(x, xb, xT);
    cast_f32_bf16<<<NSLOTS * DDIM / (256 * 8), 256, 0, stream>>>(phi_w, pwb);

    // 1. logits = x @ phi_w^T + phi_b   (MFMA NT, 2048 blocks)
    gemm_nt_bf16<true><<<dim3(NSLOTS / 128, TOKENS / 128), 256, 0, stream>>>(
        xb, pwb, phi_b, logits, TOKENS, NSLOTS, DDIM);

    // 2. dispatch/combine softmax -> bf16 D, C
    softmax_dc<<<TOKENS, 256, 0, stream>>>(logits, Db, Cb);

    // 3a. DbT = D^T bf16 [2048, 16384]
    transpose_cast<unsigned short><<<dim3(NSLOTS / 64, TOKENS / 64), 256, 0, stream>>>(
        Db, DbT, TOKENS, NSLOTS);

    // 3b. X_tilde partials = D^T @ x, split-K 8 (1024 blocks)
    gemm_nt_bf16<false>
        <<<dim3(DDIM / 128, NSLOTS / 128, KSPLIT), 256, 0, stream>>>(
            DbT, xT, nullptr, parts, NSLOTS, DDIM, TOKENS);

    // 4. reduce splits -> clip -> LN -> tanh
    reduce_ln_tanh<<<NSLOTS, 256, 0, stream>>>(parts, Xt);

    // 5. per-expert linear (fp32)
    expert_gemm<<<dim3(HDIM / 64, NEXP), 256, 0, stream>>>(
        Xt, expert_w, expert_b, Yt);

    // 5b. YtT = Yt^T bf16 [1024, 2048]
    transpose_cast<float><<<dim3(HDIM / 64, NSLOTS / 64), 256, 0, stream>>>(
        Yt, YtT, NSLOTS, HDIM);

    // 6. Y = C @ Y_tilde   (MFMA NT, 1024 blocks)
    gemm_nt_bf16<false><<<dim3(HDIM / 128, TOKENS / 128), 256, 0, stream>>>(
        Cb, YtT, nullptr, out, TOKENS, HDIM, NSLOTS);
}